// Round 10
// baseline (358.212 us; speedup 1.0000x reference)
//
#include <hip/hip_runtime.h>

typedef __attribute__((ext_vector_type(8))) short short8;
typedef __attribute__((ext_vector_type(4))) float floatx4;

static constexpr float EPS = 1e-3f;

#define CAP8  88     // max points/pillar (Poisson(33.3) +9.5 sigma, P~5e-10)
#define NB1   64     // coarse buckets (p>>9 -> 0..58 used)
#define CCAP  20480  // records per coarse bucket (mean ~16949)
#define FCAP  384    // records per fine bucket of 8 pillars (mean ~267, +7.2σ)

// ws layout: tails[4096] ints | prep (2048 f) | cbuf 59*CCAP*8 f | fgbuf 3750*FCAP*8 f
#define P_W1F  0
#define P_B1F  224
#define P_W2L  256
#define P_B2F  1280
#define P_W2UT 1312
#define PREP_F 2048

__device__ __forceinline__ unsigned short f2bf(float x) {
  unsigned u = __float_as_uint(x);
  u += 0x7FFFu + ((u >> 16) & 1u);          // RNE
  return (unsigned short)(u >> 16);
}

// ---- zero tails + fold BN weights (block 0) ----
__global__ __launch_bounds__(256)
void k_zero_prep(int* __restrict__ tails,
                 const float* __restrict__ W1, const float* __restrict__ g1,
                 const float* __restrict__ b1, const float* __restrict__ m1,
                 const float* __restrict__ v1,
                 const float* __restrict__ W2, const float* __restrict__ g2,
                 const float* __restrict__ b2, const float* __restrict__ m2,
                 const float* __restrict__ v2, float* __restrict__ prep) {
  const int id = blockIdx.x * 256 + threadIdx.x;
  if (id < 4096) tails[id] = 0;
  if (blockIdx.x == 0) {
    const int t = threadIdx.x;
    for (int i = t; i < 224; i += 256) {
      int c = i & 31;
      prep[P_W1F + i] = W1[i] * (g1[c] * rsqrtf(v1[c] + EPS));
    }
    if (t < 32) {
      float s1 = g1[t] * rsqrtf(v1[t] + EPS);
      float s2 = g2[t] * rsqrtf(v2[t] + EPS);
      prep[P_B1F + t] = b1[t] - m1[t] * s1;
      prep[P_B2F + t] = b2[t] - m2[t] * s2;
    }
    unsigned short* wt = (unsigned short*)(prep + P_W2UT);
    for (int i = t; i < 1024; i += 256) {
      int k = i >> 5, c = i & 31;
      float s2 = g2[c] * rsqrtf(v2[c] + EPS);
      prep[P_W2L + i] = W2[(32 + k) * 32 + c] * s2;   // lower half, fp32
      wt[c * 32 + k] = f2bf(W2[k * 32 + c] * s2);     // upper half, bf16, [c][k]
    }
  }
}

// ---- pass 1: points -> 64 coarse buckets (UNCHANGED from r9, proven) ----
__global__ __launch_bounds__(256)
void k_bin1(const float* __restrict__ points, const float* __restrict__ fc,
            const int* __restrict__ unq, int* __restrict__ tails,
            float* __restrict__ cbuf, int N) {
  __shared__ __align__(16) float4 orec[2048];   // 32 KB ordered records
  __shared__ int hist[NB1], sbase[NB1], gbase[NB1];
  __shared__ int dst[1024];

  const int t = threadIdx.x;
  const int tile0 = blockIdx.x * 1024;
  const int ntile = min(1024, N - tile0);
  if (t < NB1) hist[t] = 0;
  __syncthreads();

  float4 ra[4], rb[4];
  int bb[4], rr[4];
#pragma unroll
  for (int u = 0; u < 4; ++u) {
    const int j = t + u * 256;
    if (j < ntile) {
      const size_t i = (size_t)tile0 + j;
      float4 a, b;
      a.x = fc[3 * i];     a.y = fc[3 * i + 1]; a.z = fc[3 * i + 2];
      a.w = points[5 * i + 1];
      b.x = points[5 * i + 2]; b.y = points[5 * i + 3]; b.z = points[5 * i + 4];
      const int p = unq[i];
      b.w = __int_as_float(p);
      ra[u] = a; rb[u] = b;
      bb[u] = p >> 9;
      rr[u] = atomicAdd(&hist[bb[u]], 1);
    } else bb[u] = -1;
  }
  __syncthreads();

  if (t < 64) {                       // wave-0 inclusive scan over 64 buckets
    const int h = hist[t];
    int x = h;
    for (int d = 1; d < 64; d <<= 1) {
      int y = __shfl_up(x, d);
      if (t >= d) x += y;
    }
    sbase[t] = x - h;                 // exclusive base within tile
    gbase[t] = (h > 0) ? atomicAdd(&tails[t], h) : 0;
  }
  __syncthreads();

#pragma unroll
  for (int u = 0; u < 4; ++u) {
    if (bb[u] >= 0) {
      const int s = sbase[bb[u]] + rr[u];
      orec[2 * s] = ra[u];
      orec[2 * s + 1] = rb[u];
      const int gd = gbase[bb[u]] + rr[u];
      dst[s] = (gd < CCAP) ? (bb[u] * CCAP + gd) : -1;
    }
  }
  __syncthreads();

  float4* cb4 = (float4*)cbuf;        // dense flush
  for (int k2 = t; k2 < 2 * ntile; k2 += 256) {
    const int d = dst[k2 >> 1];
    if (d >= 0) cb4[(size_t)d * 2 + (k2 & 1)] = orec[k2];
  }
}

// ---- pass 2: coarse bucket -> 64 fine buckets (UNCHANGED from r9) ----
__global__ __launch_bounds__(256)
void k_bin2(const int* __restrict__ tails_ro, int* __restrict__ tails,
            const float* __restrict__ cbuf, float* __restrict__ fgbuf) {
  __shared__ __align__(16) float4 orec[2048];
  __shared__ int hist[64], sbase[64], gbase[64];
  __shared__ int dst[1024];

  const int b = blockIdx.x / 20, tl = blockIdx.x % 20;
  const int n_b = min(tails_ro[b], CCAP);
  const int tile0 = tl * 1024;
  const int ntile = min(1024, n_b - tile0);
  if (ntile <= 0) return;

  const int t = threadIdx.x;
  if (t < 64) hist[t] = 0;
  __syncthreads();

  const float4* src = (const float4*)cbuf + ((size_t)b * CCAP + tile0) * 2;
  float4 ra[4], rb[4];
  int bb[4], rr[4];
#pragma unroll
  for (int u = 0; u < 4; ++u) {
    const int j = t + u * 256;
    if (j < ntile) {
      ra[u] = src[2 * j];
      rb[u] = src[2 * j + 1];
      const int p = __float_as_int(rb[u].w);
      bb[u] = (p >> 3) & 63;
      rr[u] = atomicAdd(&hist[bb[u]], 1);
    } else bb[u] = -1;
  }
  __syncthreads();

  if (t < 64) {
    const int h = hist[t];
    int x = h;
    for (int d = 1; d < 64; d <<= 1) {
      int y = __shfl_up(x, d);
      if (t >= d) x += y;
    }
    sbase[t] = x - h;
    gbase[t] = (h > 0) ? atomicAdd(&tails[64 + (b << 6) + t], h) : 0;
  }
  __syncthreads();

#pragma unroll
  for (int u = 0; u < 4; ++u) {
    if (bb[u] >= 0) {
      const int s = sbase[bb[u]] + rr[u];
      orec[2 * s] = ra[u];
      orec[2 * s + 1] = rb[u];
      const int gd = gbase[bb[u]] + rr[u];
      dst[s] = (gd < FCAP) ? (((b << 6) + bb[u]) * FCAP + gd) : -1;
    }
  }
  __syncthreads();

  float4* fb4 = (float4*)fgbuf;
  for (int k2 = t; k2 < 2 * ntile; k2 += 256) {
    const int d = dst[k2 >> 1];
    if (d >= 0) fb4[(size_t)d * 2 + (k2 & 1)] = orec[k2];
  }
}

// ---- pillar v2 (r10): 512 thr, wave=pillar, occupancy-first ----
// r9 regression diagnosis: 77KB LDS -> 2 blk/CU -> 17.9% occupancy; fbuf
// binning scatter + 64B-stride hbuf reads -> 1.7M bank conflicts.
// Fix: no fbuf — stage records ARRIVAL-order (dense), slot-assign via 8 LDS
// counters; phase 1 writes bf16 h straight to per-pillar hbuf (XOR-swizzled:
// u16 idx ^= ((row>>1)&3)<<3 -> phase-3 ds_read_b128 8-way -> 2-way) and
// accumulates channel sums with ds_add_f32 (32 distinct banks/half-wave).
// LDS 61KB, 512 thr -> 16 waves/CU (2x r9).
__global__ __launch_bounds__(512)
void k_pillar(const float* __restrict__ prep, const int* __restrict__ tails,
              const float* __restrict__ fgbuf, float* __restrict__ out,
              int npil) {
  __shared__ __align__(16) float rec[FCAP][8];                  // 12 KB
  __shared__ unsigned short slotrec[FCAP];                      // 0.75 KB
  __shared__ __align__(16) unsigned short hbuf[8 * CAP8 * 32];  // 44 KB
  __shared__ __align__(16) unsigned short w2t[1024];            // 2 KB
  __shared__ __align__(16) float sumb[8][32];                   // 1 KB
  __shared__ int cnt8[8];

  const int t = threadIdx.x;
  if (t < 256) ((uint2*)w2t)[t] = ((const uint2*)(prep + P_W2UT))[t];
  if (t < 256) ((float*)sumb)[t] = 0.f;
  if (t < 8) cnt8[t] = 0;
  __syncthreads();

  const int fb = blockIdx.x;
  const int nrec = min(tails[64 + fb], FCAP);

  // stage arrival-order + per-pillar slot assignment (8-counter histogram)
  const float4* src = (const float4*)(fgbuf + (size_t)fb * FCAP * 8);
  for (int j = t; j < nrec; j += 512) {
    float4 a = src[2 * j], b = src[2 * j + 1];
    ((float4*)rec[j])[0] = a;
    ((float4*)rec[j])[1] = b;
    const int pl = __float_as_int(b.w) & 7;
    const int slot = atomicAdd(&cnt8[pl], 1);
    slotrec[j] = (slot < CAP8)
                     ? (unsigned short)((pl << 12) | (pl * CAP8 + slot))
                     : 0xFFFFu;
  }
  __syncthreads();

  const int c = t & 31, hw = t >> 5;    // 16 half-waves, lane c = channel
  float w1c[7];
#pragma unroll
  for (int r = 0; r < 7; ++r) w1c[r] = prep[P_W1F + r * 32 + c];
  const float b1c = prep[P_B1F + c];
  const float b2c = prep[P_B2F + c];

  // phase 1: h = relu(f.w1f + b1f); ds_add_f32 channel sums (fp32, r0-exact);
  // bf16 h -> swizzled per-pillar hbuf row
  for (int j = hw; j < nrec; j += 16) {
    const unsigned se = slotrec[j];
    const floatx4 fa = *(const floatx4*)rec[j];          // LDS broadcast
    const floatx4 fv = *(const floatx4*)(rec[j] + 4);
    float d = fa.x * w1c[0];
    d = fmaf(fa.y, w1c[1], d);
    d = fmaf(fa.z, w1c[2], d);
    d = fmaf(fa.w, w1c[3], d);
    d = fmaf(fv.x, w1c[4], d);
    d = fmaf(fv.y, w1c[5], d);
    d = fmaf(fv.z, w1c[6], d);
    const float h = fmaxf(d + b1c, 0.f);
    if (se != 0xFFFFu) {
      const int row = se & 0xFFF, pl = se >> 12;
      atomicAdd(&sumb[pl][c], h);        // ds_add_f32, banks=c: conflict-free
      hbuf[row * 32 + (c ^ (((row >> 1) & 3) << 3))] = f2bf(h);
    }
  }
  __syncthreads();

  // per-wave: wave w owns pillar fb*8+w
  const int w = t >> 6, lane = t & 63;
  const int p = fb * 8 + w;
  if (p >= npil) return;
  int n = cnt8[w];
  n = n < CAP8 ? n : CAP8;

  // phase 2: pc[c] = b2f + (sum_k sumh[k]*w2l[k][c]) / n
  float acc = 0.f;
  const floatx4* sb4 = (const floatx4*)sumb[w];
#pragma unroll
  for (int kq = 0; kq < 8; ++kq) {
    floatx4 sv = sb4[kq];
    acc = fmaf(sv.x, prep[P_W2L + (kq * 4 + 0) * 32 + c], acc);
    acc = fmaf(sv.y, prep[P_W2L + (kq * 4 + 1) * 32 + c], acc);
    acc = fmaf(sv.z, prep[P_W2L + (kq * 4 + 2) * 32 + c], acc);
    acc = fmaf(sv.w, prep[P_W2L + (kq * 4 + 3) * 32 + c], acc);
  }
  const float inv_n = (n > 0) ? 1.f / (float)n : 1.f;
  const float pc = fmaf(inv_n, acc, b2c);

  // phase 3: Q = H(bf16) @ W2u via MFMA on swizzled hbuf; masked row-max
  const int m16 = lane & 15, q4 = lane >> 4;
  const short8 bf0 = *(const short8*)(w2t + m16 * 32 + q4 * 8);
  const short8 bf1 = *(const short8*)(w2t + (m16 + 16) * 32 + q4 * 8);
  float m0 = -INFINITY, m1 = -INFINITY;
  const int ntiles = (n + 15) >> 4;
  for (int rt = 0; rt < ntiles; ++rt) {
    const int row = w * CAP8 + rt * 16 + m16;
    short8 af = *(const short8*)(hbuf + row * 32 +
                                 ((q4 ^ ((row >> 1) & 3)) << 3));
    floatx4 z = {0.f, 0.f, 0.f, 0.f};
    floatx4 a0 = __builtin_amdgcn_mfma_f32_16x16x32_bf16(af, bf0, z, 0, 0, 0);
    floatx4 a1 = __builtin_amdgcn_mfma_f32_16x16x32_bf16(af, bf1, z, 0, 0, 0);
    const int rowb = rt * 16 + q4 * 4;
#pragma unroll
    for (int r = 0; r < 4; ++r) {
      if (rowb + r < n) {              // mask tail-tile garbage rows
        m0 = fmaxf(m0, a0[r]);
        m1 = fmaxf(m1, a1[r]);
      }
    }
  }
  m0 = fmaxf(m0, __shfl_xor(m0, 16));
  m0 = fmaxf(m0, __shfl_xor(m0, 32));
  m1 = fmaxf(m1, __shfl_xor(m1, 16));
  m1 = fmaxf(m1, __shfl_xor(m1, 32));

  if (lane < 32) {
    float q = (lane & 16) ? m1 : m0;
    out[p * 32 + lane] = fmaxf(q + pc, 0.f);   // relu(max+pc): s2>0 monotone
  }
}

extern "C" void kernel_launch(void* const* d_in, const int* in_sizes, int n_in,
                              void* d_out, int out_size, void* d_ws, size_t ws_size,
                              hipStream_t stream) {
  const float* points = (const float*)d_in[0];
  const float* fc     = (const float*)d_in[1];
  const int*   unq    = (const int*)d_in[2];
  const float* W1 = (const float*)d_in[3];
  const float* g1 = (const float*)d_in[4];
  const float* b1 = (const float*)d_in[5];
  const float* m1 = (const float*)d_in[6];
  const float* v1 = (const float*)d_in[7];
  const float* W2 = (const float*)d_in[8];
  const float* g2 = (const float*)d_in[9];
  const float* b2 = (const float*)d_in[10];
  const float* m2 = (const float*)d_in[11];
  const float* v2 = (const float*)d_in[12];

  const int N    = in_sizes[0] / 5;  // 1,000,000
  const int NPIL = out_size / 32;    // 30,000

  float* ws = (float*)d_ws;
  int* tails = (int*)ws;
  float* prep = ws + 4096;
  float* cbuf = prep + PREP_F;
  float* fgbuf = cbuf + (size_t)59 * CCAP * 8;

  k_zero_prep<<<16, 256, 0, stream>>>(tails, W1, g1, b1, m1, v1,
                                      W2, g2, b2, m2, v2, prep);

  k_bin1<<<(N + 1023) / 1024, 256, 0, stream>>>(points, fc, unq, tails, cbuf, N);

  k_bin2<<<59 * 20, 256, 0, stream>>>(tails, tails, cbuf, fgbuf);

  const int nfb = (NPIL + 7) / 8;    // 3750
  k_pillar<<<nfb, 512, 0, stream>>>(prep, tails, fgbuf, (float*)d_out, NPIL);
}

// Round 11
// 192.801 us; speedup vs baseline: 1.8579x; 1.8579x over previous
//
#include <hip/hip_runtime.h>

typedef __attribute__((ext_vector_type(8))) short short8;
typedef __attribute__((ext_vector_type(4))) float floatx4;

static constexpr float EPS = 1e-3f;

#define CAP8  88     // max points/pillar (Poisson(33.3) +9.5 sigma)
#define NB1   64     // coarse buckets (p>>9 -> 0..58 used)
#define CCAP  20480  // records per coarse bucket (mean ~16949)
#define FCAP  384    // records per fine bucket of 8 pillars (mean ~267, +7.2σ)

// ws layout: tails[4096] ints | prep (2048 f) | cbuf 59*CCAP*8 f | fgbuf 3750*FCAP*8 f
#define P_W1F  0
#define P_B1F  224
#define P_W2L  256
#define P_B2F  1280
#define P_W2UT 1312
#define PREP_F 2048

__device__ __forceinline__ unsigned short f2bf(float x) {
  unsigned u = __float_as_uint(x);
  u += 0x7FFFu + ((u >> 16) & 1u);          // RNE
  return (unsigned short)(u >> 16);
}

// ---- zero tails + fold BN weights (block 0) ----
__global__ __launch_bounds__(256)
void k_zero_prep(int* __restrict__ tails,
                 const float* __restrict__ W1, const float* __restrict__ g1,
                 const float* __restrict__ b1, const float* __restrict__ m1,
                 const float* __restrict__ v1,
                 const float* __restrict__ W2, const float* __restrict__ g2,
                 const float* __restrict__ b2, const float* __restrict__ m2,
                 const float* __restrict__ v2, float* __restrict__ prep) {
  const int id = blockIdx.x * 256 + threadIdx.x;
  if (id < 4096) tails[id] = 0;
  if (blockIdx.x == 0) {
    const int t = threadIdx.x;
    for (int i = t; i < 224; i += 256) {
      int c = i & 31;
      prep[P_W1F + i] = W1[i] * (g1[c] * rsqrtf(v1[c] + EPS));
    }
    if (t < 32) {
      float s1 = g1[t] * rsqrtf(v1[t] + EPS);
      float s2 = g2[t] * rsqrtf(v2[t] + EPS);
      prep[P_B1F + t] = b1[t] - m1[t] * s1;
      prep[P_B2F + t] = b2[t] - m2[t] * s2;
    }
    unsigned short* wt = (unsigned short*)(prep + P_W2UT);
    for (int i = t; i < 1024; i += 256) {
      int k = i >> 5, c = i & 31;
      float s2 = g2[c] * rsqrtf(v2[c] + EPS);
      prep[P_W2L + i] = W2[(32 + k) * 32 + c] * s2;   // lower half, fp32
      wt[c * 32 + k] = f2bf(W2[k * 32 + c] * s2);     // upper half, bf16, [c][k]
    }
  }
}

// ---- pass 1: points -> 64 coarse buckets (UNCHANGED, proven r9/r10) ----
__global__ __launch_bounds__(256)
void k_bin1(const float* __restrict__ points, const float* __restrict__ fc,
            const int* __restrict__ unq, int* __restrict__ tails,
            float* __restrict__ cbuf, int N) {
  __shared__ __align__(16) float4 orec[2048];   // 32 KB ordered records
  __shared__ int hist[NB1], sbase[NB1], gbase[NB1];
  __shared__ int dst[1024];

  const int t = threadIdx.x;
  const int tile0 = blockIdx.x * 1024;
  const int ntile = min(1024, N - tile0);
  if (t < NB1) hist[t] = 0;
  __syncthreads();

  float4 ra[4], rb[4];
  int bb[4], rr[4];
#pragma unroll
  for (int u = 0; u < 4; ++u) {
    const int j = t + u * 256;
    if (j < ntile) {
      const size_t i = (size_t)tile0 + j;
      float4 a, b;
      a.x = fc[3 * i];     a.y = fc[3 * i + 1]; a.z = fc[3 * i + 2];
      a.w = points[5 * i + 1];
      b.x = points[5 * i + 2]; b.y = points[5 * i + 3]; b.z = points[5 * i + 4];
      const int p = unq[i];
      b.w = __int_as_float(p);
      ra[u] = a; rb[u] = b;
      bb[u] = p >> 9;
      rr[u] = atomicAdd(&hist[bb[u]], 1);
    } else bb[u] = -1;
  }
  __syncthreads();

  if (t < 64) {                       // wave-0 inclusive scan over 64 buckets
    const int h = hist[t];
    int x = h;
    for (int d = 1; d < 64; d <<= 1) {
      int y = __shfl_up(x, d);
      if (t >= d) x += y;
    }
    sbase[t] = x - h;                 // exclusive base within tile
    gbase[t] = (h > 0) ? atomicAdd(&tails[t], h) : 0;
  }
  __syncthreads();

#pragma unroll
  for (int u = 0; u < 4; ++u) {
    if (bb[u] >= 0) {
      const int s = sbase[bb[u]] + rr[u];
      orec[2 * s] = ra[u];
      orec[2 * s + 1] = rb[u];
      const int gd = gbase[bb[u]] + rr[u];
      dst[s] = (gd < CCAP) ? (bb[u] * CCAP + gd) : -1;
    }
  }
  __syncthreads();

  float4* cb4 = (float4*)cbuf;        // dense flush
  for (int k2 = t; k2 < 2 * ntile; k2 += 256) {
    const int d = dst[k2 >> 1];
    if (d >= 0) cb4[(size_t)d * 2 + (k2 & 1)] = orec[k2];
  }
}

// ---- pass 2: coarse bucket -> 64 fine buckets (UNCHANGED, proven) ----
__global__ __launch_bounds__(256)
void k_bin2(const int* __restrict__ tails_ro, int* __restrict__ tails,
            const float* __restrict__ cbuf, float* __restrict__ fgbuf) {
  __shared__ __align__(16) float4 orec[2048];
  __shared__ int hist[64], sbase[64], gbase[64];
  __shared__ int dst[1024];

  const int b = blockIdx.x / 20, tl = blockIdx.x % 20;
  const int n_b = min(tails_ro[b], CCAP);
  const int tile0 = tl * 1024;
  const int ntile = min(1024, n_b - tile0);
  if (ntile <= 0) return;

  const int t = threadIdx.x;
  if (t < 64) hist[t] = 0;
  __syncthreads();

  const float4* src = (const float4*)cbuf + ((size_t)b * CCAP + tile0) * 2;
  float4 ra[4], rb[4];
  int bb[4], rr[4];
#pragma unroll
  for (int u = 0; u < 4; ++u) {
    const int j = t + u * 256;
    if (j < ntile) {
      ra[u] = src[2 * j];
      rb[u] = src[2 * j + 1];
      const int p = __float_as_int(rb[u].w);
      bb[u] = (p >> 3) & 63;
      rr[u] = atomicAdd(&hist[bb[u]], 1);
    } else bb[u] = -1;
  }
  __syncthreads();

  if (t < 64) {
    const int h = hist[t];
    int x = h;
    for (int d = 1; d < 64; d <<= 1) {
      int y = __shfl_up(x, d);
      if (t >= d) x += y;
    }
    sbase[t] = x - h;
    gbase[t] = (h > 0) ? atomicAdd(&tails[64 + (b << 6) + t], h) : 0;
  }
  __syncthreads();

#pragma unroll
  for (int u = 0; u < 4; ++u) {
    if (bb[u] >= 0) {
      const int s = sbase[bb[u]] + rr[u];
      orec[2 * s] = ra[u];
      orec[2 * s + 1] = rb[u];
      const int gd = gbase[bb[u]] + rr[u];
      dst[s] = (gd < FCAP) ? (((b << 6) + bb[u]) * FCAP + gd) : -1;
    }
  }
  __syncthreads();

  float4* fb4 = (float4*)fgbuf;
  for (int k2 = t; k2 < 2 * ntile; k2 += 256) {
    const int d = dst[k2 >> 1];
    if (d >= 0) fb4[(size_t)d * 2 + (k2 & 1)] = orec[k2];
  }
}

// ---- pillar v3 (r11): r10 shape MINUS LDS float atomics ----
// r10 diagnosis: 8.5k ds_add_f32 lane-RMWs/block serialized at the LDS unit
// = the 200us. Fix: staging builds inverse map ord[pl][slot]=j (int LDS
// atomics only, 384/block); phase 1 is pillar-ordered per wave (r9-style)
// with REGISTER fp32 channel sums + one shfl_xor. No fp atomics anywhere.
__global__ __launch_bounds__(512)
void k_pillar(const float* __restrict__ prep, const int* __restrict__ tails,
              const float* __restrict__ fgbuf, float* __restrict__ out,
              int npil) {
  __shared__ __align__(16) float rec[FCAP][8];                  // 12 KB
  __shared__ unsigned short ord[8][CAP8];                       // 1.4 KB
  __shared__ __align__(16) unsigned short hbuf[8 * CAP8 * 32];  // 44 KB
  __shared__ __align__(16) unsigned short w2t[1024];            // 2 KB
  __shared__ __align__(16) float sumb[8][32];                   // 1 KB
  __shared__ int cnt8[8];

  const int t = threadIdx.x;
  if (t < 256) ((uint2*)w2t)[t] = ((const uint2*)(prep + P_W2UT))[t];
  if (t < 8) cnt8[t] = 0;
  __syncthreads();

  const int fb = blockIdx.x;
  const int nrec = min(tails[64 + fb], FCAP);

  // stage arrival-order records + build per-pillar inverse map
  const float4* src = (const float4*)(fgbuf + (size_t)fb * FCAP * 8);
  for (int j = t; j < nrec; j += 512) {
    float4 a = src[2 * j], b = src[2 * j + 1];
    ((float4*)rec[j])[0] = a;
    ((float4*)rec[j])[1] = b;
    const int pl = __float_as_int(b.w) & 7;
    const int slot = atomicAdd(&cnt8[pl], 1);    // ds_add_rtn_u32 (native int)
    if (slot < CAP8) ord[pl][slot] = (unsigned short)j;
  }
  __syncthreads();

  // wave w owns pillar fb*8+w
  const int w = t >> 6, lane = t & 63;
  const int c = lane & 31, half = lane >> 5;
  const int p = fb * 8 + w;
  if (p >= npil) return;
  int n = cnt8[w];
  n = n < CAP8 ? n : CAP8;

  float w1c[7];
#pragma unroll
  for (int r = 0; r < 7; ++r) w1c[r] = prep[P_W1F + r * 32 + c];
  const float b1c = prep[P_B1F + c];
  const float b2c = prep[P_B2F + c];

  // phase 1: pillar-ordered; register fp32 sums; bf16 h -> swizzled hbuf
  float ps = 0.f;
  const int rbase = w * CAP8;
#pragma unroll 2
  for (int s = half; s < n; s += 2) {
    const int j = ord[w][s];
    const floatx4 fa = *(const floatx4*)rec[j];      // LDS broadcast (16B)
    const floatx4 fv = *(const floatx4*)(rec[j] + 4);
    float d = fa.x * w1c[0];
    d = fmaf(fa.y, w1c[1], d);
    d = fmaf(fa.z, w1c[2], d);
    d = fmaf(fa.w, w1c[3], d);
    d = fmaf(fv.x, w1c[4], d);
    d = fmaf(fv.y, w1c[5], d);
    d = fmaf(fv.z, w1c[6], d);
    const float h = fmaxf(d + b1c, 0.f);
    ps += h;
    const int row = rbase + s;
    hbuf[row * 32 + (c ^ (((row >> 1) & 3) << 3))] = f2bf(h);
  }
  ps += __shfl_xor(ps, 32);              // cross-half channel sum
  if (half == 0) sumb[w][c] = ps;
  __builtin_amdgcn_wave_barrier();

  // phase 2: pc[c] = b2f + (sum_k sumh[k]*w2l[k][c]) / n
  float acc = 0.f;
  const floatx4* sb4 = (const floatx4*)sumb[w];
#pragma unroll
  for (int kq = 0; kq < 8; ++kq) {
    floatx4 sv = sb4[kq];
    acc = fmaf(sv.x, prep[P_W2L + (kq * 4 + 0) * 32 + c], acc);
    acc = fmaf(sv.y, prep[P_W2L + (kq * 4 + 1) * 32 + c], acc);
    acc = fmaf(sv.z, prep[P_W2L + (kq * 4 + 2) * 32 + c], acc);
    acc = fmaf(sv.w, prep[P_W2L + (kq * 4 + 3) * 32 + c], acc);
  }
  const float inv_n = (n > 0) ? 1.f / (float)n : 1.f;
  const float pc = fmaf(inv_n, acc, b2c);

  // phase 3: Q = H(bf16) @ W2u via MFMA on swizzled hbuf; masked row-max
  const int m16 = lane & 15, q4 = lane >> 4;
  const short8 bf0 = *(const short8*)(w2t + m16 * 32 + q4 * 8);
  const short8 bf1 = *(const short8*)(w2t + (m16 + 16) * 32 + q4 * 8);
  float m0 = -INFINITY, m1 = -INFINITY;
  const int ntiles = (n + 15) >> 4;
  for (int rt = 0; rt < ntiles; ++rt) {
    const int row = rbase + rt * 16 + m16;
    short8 af = *(const short8*)(hbuf + row * 32 +
                                 ((q4 ^ ((row >> 1) & 3)) << 3));
    floatx4 z = {0.f, 0.f, 0.f, 0.f};
    floatx4 a0 = __builtin_amdgcn_mfma_f32_16x16x32_bf16(af, bf0, z, 0, 0, 0);
    floatx4 a1 = __builtin_amdgcn_mfma_f32_16x16x32_bf16(af, bf1, z, 0, 0, 0);
    const int rowb = rt * 16 + q4 * 4;
#pragma unroll
    for (int r = 0; r < 4; ++r) {
      if (rowb + r < n) {              // mask tail-tile garbage rows
        m0 = fmaxf(m0, a0[r]);
        m1 = fmaxf(m1, a1[r]);
      }
    }
  }
  m0 = fmaxf(m0, __shfl_xor(m0, 16));
  m0 = fmaxf(m0, __shfl_xor(m0, 32));
  m1 = fmaxf(m1, __shfl_xor(m1, 16));
  m1 = fmaxf(m1, __shfl_xor(m1, 32));

  if (lane < 32) {
    float q = (lane & 16) ? m1 : m0;
    out[p * 32 + lane] = fmaxf(q + pc, 0.f);   // relu(max+pc): s2>0 monotone
  }
}

extern "C" void kernel_launch(void* const* d_in, const int* in_sizes, int n_in,
                              void* d_out, int out_size, void* d_ws, size_t ws_size,
                              hipStream_t stream) {
  const float* points = (const float*)d_in[0];
  const float* fc     = (const float*)d_in[1];
  const int*   unq    = (const int*)d_in[2];
  const float* W1 = (const float*)d_in[3];
  const float* g1 = (const float*)d_in[4];
  const float* b1 = (const float*)d_in[5];
  const float* m1 = (const float*)d_in[6];
  const float* v1 = (const float*)d_in[7];
  const float* W2 = (const float*)d_in[8];
  const float* g2 = (const float*)d_in[9];
  const float* b2 = (const float*)d_in[10];
  const float* m2 = (const float*)d_in[11];
  const float* v2 = (const float*)d_in[12];

  const int N    = in_sizes[0] / 5;  // 1,000,000
  const int NPIL = out_size / 32;    // 30,000

  float* ws = (float*)d_ws;
  int* tails = (int*)ws;
  float* prep = ws + 4096;
  float* cbuf = prep + PREP_F;
  float* fgbuf = cbuf + (size_t)59 * CCAP * 8;

  k_zero_prep<<<16, 256, 0, stream>>>(tails, W1, g1, b1, m1, v1,
                                      W2, g2, b2, m2, v2, prep);

  k_bin1<<<(N + 1023) / 1024, 256, 0, stream>>>(points, fc, unq, tails, cbuf, N);

  k_bin2<<<59 * 20, 256, 0, stream>>>(tails, tails, cbuf, fgbuf);

  const int nfb = (NPIL + 7) / 8;    // 3750
  k_pillar<<<nfb, 512, 0, stream>>>(prep, tails, fgbuf, (float*)d_out, NPIL);
}

// Round 12
// 167.911 us; speedup vs baseline: 2.1334x; 1.1482x over previous
//
#include <hip/hip_runtime.h>

typedef __attribute__((ext_vector_type(8))) short short8;
typedef __attribute__((ext_vector_type(4))) float floatx4;

static constexpr float EPS = 1e-3f;

#define CAP8  88     // max points/pillar (Poisson(33.3) +9.5 sigma)
#define NB1   64     // coarse buckets (p>>9 -> 0..58 used)
#define CCAP  20480  // records per coarse bucket (mean ~16949); 10*2048
#define FCAP  384    // records per fine bucket of 8 pillars (mean ~267, +7.2σ)

// ws layout: tails[4096] ints | prep (2048 f) | row8 N*8 f | cbuf 59*CCAP int2
//            | fgbuf 3750*FCAP int2
#define P_W1F  0
#define P_B1F  224
#define P_W2L  256
#define P_B2F  1280
#define P_W2UT 1312
#define PREP_F 2048

__device__ __forceinline__ unsigned short f2bf(float x) {
  unsigned u = __float_as_uint(x);
  u += 0x7FFFu + ((u >> 16) & 1u);          // RNE
  return (unsigned short)(u >> 16);
}

// ---- fused: zero tails + fold BN weights (block 0) + build row8 stream ----
// r11 lesson: bins at 32B/record move 128MB at 1.8TB/s = ~70us. Fix: bins
// carry 8B {idx,p}; the payload is written ONCE here as a sequential stream
// (the only write pattern that runs at payload rate, r3) and gathered
// L3-resident in k_pillar staging.
__global__ __launch_bounds__(256)
void k_prep_row8(const float* __restrict__ points, const float* __restrict__ fc,
                 int* __restrict__ tails, float* __restrict__ row8,
                 const float* __restrict__ W1, const float* __restrict__ g1,
                 const float* __restrict__ b1, const float* __restrict__ m1,
                 const float* __restrict__ v1,
                 const float* __restrict__ W2, const float* __restrict__ g2,
                 const float* __restrict__ b2, const float* __restrict__ m2,
                 const float* __restrict__ v2, float* __restrict__ prep,
                 int N) {
  const int gid = blockIdx.x * 256 + threadIdx.x;
  if (gid < 4096) tails[gid] = 0;
  if (blockIdx.x == 0) {
    const int t = threadIdx.x;
    for (int i = t; i < 224; i += 256) {
      int c = i & 31;
      prep[P_W1F + i] = W1[i] * (g1[c] * rsqrtf(v1[c] + EPS));
    }
    if (t < 32) {
      float s1 = g1[t] * rsqrtf(v1[t] + EPS);
      float s2 = g2[t] * rsqrtf(v2[t] + EPS);
      prep[P_B1F + t] = b1[t] - m1[t] * s1;
      prep[P_B2F + t] = b2[t] - m2[t] * s2;
    }
    unsigned short* wt = (unsigned short*)(prep + P_W2UT);
    for (int i = t; i < 1024; i += 256) {
      int k = i >> 5, c = i & 31;
      float s2 = g2[c] * rsqrtf(v2[c] + EPS);
      prep[P_W2L + i] = W2[(32 + k) * 32 + c] * s2;   // lower half, fp32
      wt[c * 32 + k] = f2bf(W2[k * 32 + c] * s2);     // upper half, bf16, [c][k]
    }
  }
  if (gid < N) {
    const size_t i = (size_t)gid;
    float4 a, b;
    a.x = fc[3 * i];     a.y = fc[3 * i + 1]; a.z = fc[3 * i + 2];
    a.w = points[5 * i + 1];
    b.x = points[5 * i + 2]; b.y = points[5 * i + 3]; b.z = points[5 * i + 4];
    b.w = 0.f;
    float4* dst = (float4*)(row8 + i * 8);
    dst[0] = a;
    dst[1] = b;
  }
}

// ---- pass 1: unq -> 64 coarse buckets of {idx,p} (8B records) ----
// tile=2048, 8 records/thread via 2x int4 loads (N%8==0 -> no straddle)
__global__ __launch_bounds__(256)
void k_bin1(const int* __restrict__ unq, int* __restrict__ tails,
            int2* __restrict__ cbuf, int N) {
  __shared__ int2 orec[2048];                 // 16 KB ordered records
  __shared__ int dst[2048];                   // 8 KB
  __shared__ int hist[NB1], sbase[NB1], gbase[NB1];

  const int t = threadIdx.x;
  const int tile0 = blockIdx.x * 2048;
  const int ntile = min(2048, N - tile0);     // multiple of 8 (N=1e6)
  if (t < NB1) hist[t] = 0;
  __syncthreads();

  int pv[8], rr[8], bb[8];
  const int lbase = t * 8;
  if (lbase < ntile) {
    const int4* u4 = (const int4*)(unq + tile0 + lbase);
    int4 ua = u4[0], ub = u4[1];
    pv[0] = ua.x; pv[1] = ua.y; pv[2] = ua.z; pv[3] = ua.w;
    pv[4] = ub.x; pv[5] = ub.y; pv[6] = ub.z; pv[7] = ub.w;
#pragma unroll
    for (int u = 0; u < 8; ++u) {
      bb[u] = pv[u] >> 9;
      rr[u] = atomicAdd(&hist[bb[u]], 1);
    }
  } else {
#pragma unroll
    for (int u = 0; u < 8; ++u) bb[u] = -1;
  }
  __syncthreads();

  if (t < 64) {                               // wave-0 scan over 64 buckets
    const int h = hist[t];
    int x = h;
    for (int d = 1; d < 64; d <<= 1) {
      int y = __shfl_up(x, d);
      if (t >= d) x += y;
    }
    sbase[t] = x - h;
    gbase[t] = (h > 0) ? atomicAdd(&tails[t], h) : 0;
  }
  __syncthreads();

  if (bb[0] >= 0) {
#pragma unroll
    for (int u = 0; u < 8; ++u) {
      const int s = sbase[bb[u]] + rr[u];
      orec[s] = make_int2(tile0 + lbase + u, pv[u]);
      const int gd = gbase[bb[u]] + rr[u];
      dst[s] = (gd < CCAP) ? (bb[u] * CCAP + gd) : -1;
    }
  }
  __syncthreads();

  for (int k = t; k < ntile; k += 256) {      // dense segment flush (8B/lane)
    const int d = dst[k];
    if (d >= 0) cbuf[d] = orec[k];
  }
}

// ---- pass 2: coarse bucket -> 64 fine buckets (8 pillars each) ----
__global__ __launch_bounds__(256)
void k_bin2(const int* __restrict__ tails_ro, int* __restrict__ tails,
            const int2* __restrict__ cbuf, int2* __restrict__ fgbuf) {
  __shared__ int2 orec[2048];
  __shared__ int dst[2048];
  __shared__ int hist[64], sbase[64], gbase[64];

  const int b = blockIdx.x / 10, tl = blockIdx.x % 10;
  const int n_b = min(tails_ro[b], CCAP);
  const int tile0 = tl * 2048;
  const int ntile = min(2048, n_b - tile0);
  if (ntile <= 0) return;

  const int t = threadIdx.x;
  if (t < 64) hist[t] = 0;
  __syncthreads();

  const int2* src = cbuf + (size_t)b * CCAP + tile0;
  int2 rv[8];
  int rr[8], bb[8];
  const int lbase = t * 8;
#pragma unroll
  for (int u = 0; u < 8; ++u) {
    const int j = lbase + u;
    if (j < ntile) {                          // loads within CCAP region: safe
      rv[u] = src[j];
      bb[u] = (rv[u].y >> 3) & 63;
      rr[u] = atomicAdd(&hist[bb[u]], 1);
    } else bb[u] = -1;
  }
  __syncthreads();

  if (t < 64) {
    const int h = hist[t];
    int x = h;
    for (int d = 1; d < 64; d <<= 1) {
      int y = __shfl_up(x, d);
      if (t >= d) x += y;
    }
    sbase[t] = x - h;
    gbase[t] = (h > 0) ? atomicAdd(&tails[64 + (b << 6) + t], h) : 0;
  }
  __syncthreads();

#pragma unroll
  for (int u = 0; u < 8; ++u) {
    if (bb[u] >= 0) {
      const int s = sbase[bb[u]] + rr[u];
      orec[s] = rv[u];
      const int gd = gbase[bb[u]] + rr[u];
      dst[s] = (gd < FCAP) ? (((b << 6) + bb[u]) * FCAP + gd) : -1;
    }
  }
  __syncthreads();

  for (int k = t; k < ntile; k += 256) {
    const int d = dst[k];
    if (d >= 0) fgbuf[d] = orec[k];
  }
}

// ---- pillar v4 (r12): r11 compute, staging gathers row8 via idx ----
__global__ __launch_bounds__(512)
void k_pillar(const float* __restrict__ prep, const int* __restrict__ tails,
              const int2* __restrict__ fgbuf, const float* __restrict__ row8,
              float* __restrict__ out, int npil) {
  __shared__ __align__(16) float rec[FCAP][8];                  // 12 KB
  __shared__ unsigned short ord[8][CAP8];                       // 1.4 KB
  __shared__ __align__(16) unsigned short hbuf[8 * CAP8 * 32];  // 44 KB
  __shared__ __align__(16) unsigned short w2t[1024];            // 2 KB
  __shared__ __align__(16) float sumb[8][32];                   // 1 KB
  __shared__ int cnt8[8];

  const int t = threadIdx.x;
  if (t < 256) ((uint2*)w2t)[t] = ((const uint2*)(prep + P_W2UT))[t];
  if (t < 8) cnt8[t] = 0;
  __syncthreads();

  const int fb = blockIdx.x;
  const int nrec = min(tails[64 + fb], FCAP);

  // staging: sequential 8B rec read + L3-resident row8 gather (1 line/rec),
  // 512 threads in parallel -> latency amortized. Int LDS atomics only.
  const int2* src = fgbuf + (size_t)fb * FCAP;
  for (int j = t; j < nrec; j += 512) {
    const int2 r = src[j];
    const floatx4* rp = (const floatx4*)(row8 + (size_t)r.x * 8);
    ((floatx4*)rec[j])[0] = rp[0];
    ((floatx4*)rec[j])[1] = rp[1];
    const int pl = r.y & 7;
    const int slot = atomicAdd(&cnt8[pl], 1);    // ds_add_rtn_u32
    if (slot < CAP8) ord[pl][slot] = (unsigned short)j;
  }
  __syncthreads();

  // wave w owns pillar fb*8+w
  const int w = t >> 6, lane = t & 63;
  const int c = lane & 31, half = lane >> 5;
  const int p = fb * 8 + w;
  if (p >= npil) return;
  int n = cnt8[w];
  n = n < CAP8 ? n : CAP8;

  float w1c[7];
#pragma unroll
  for (int r = 0; r < 7; ++r) w1c[r] = prep[P_W1F + r * 32 + c];
  const float b1c = prep[P_B1F + c];
  const float b2c = prep[P_B2F + c];

  // phase 1: pillar-ordered; register fp32 sums; bf16 h -> swizzled hbuf
  float ps = 0.f;
  const int rbase = w * CAP8;
#pragma unroll 2
  for (int s = half; s < n; s += 2) {
    const int j = ord[w][s];
    const floatx4 fa = *(const floatx4*)rec[j];      // LDS broadcast (16B)
    const floatx4 fv = *(const floatx4*)(rec[j] + 4);
    float d = fa.x * w1c[0];
    d = fmaf(fa.y, w1c[1], d);
    d = fmaf(fa.z, w1c[2], d);
    d = fmaf(fa.w, w1c[3], d);
    d = fmaf(fv.x, w1c[4], d);
    d = fmaf(fv.y, w1c[5], d);
    d = fmaf(fv.z, w1c[6], d);
    const float h = fmaxf(d + b1c, 0.f);
    ps += h;
    const int row = rbase + s;
    hbuf[row * 32 + (c ^ (((row >> 1) & 3) << 3))] = f2bf(h);
  }
  ps += __shfl_xor(ps, 32);              // cross-half channel sum
  if (half == 0) sumb[w][c] = ps;
  __builtin_amdgcn_wave_barrier();

  // phase 2: pc[c] = b2f + (sum_k sumh[k]*w2l[k][c]) / n
  float acc = 0.f;
  const floatx4* sb4 = (const floatx4*)sumb[w];
#pragma unroll
  for (int kq = 0; kq < 8; ++kq) {
    floatx4 sv = sb4[kq];
    acc = fmaf(sv.x, prep[P_W2L + (kq * 4 + 0) * 32 + c], acc);
    acc = fmaf(sv.y, prep[P_W2L + (kq * 4 + 1) * 32 + c], acc);
    acc = fmaf(sv.z, prep[P_W2L + (kq * 4 + 2) * 32 + c], acc);
    acc = fmaf(sv.w, prep[P_W2L + (kq * 4 + 3) * 32 + c], acc);
  }
  const float inv_n = (n > 0) ? 1.f / (float)n : 1.f;
  const float pc = fmaf(inv_n, acc, b2c);

  // phase 3: Q = H(bf16) @ W2u via MFMA on swizzled hbuf; masked row-max
  const int m16 = lane & 15, q4 = lane >> 4;
  const short8 bf0 = *(const short8*)(w2t + m16 * 32 + q4 * 8);
  const short8 bf1 = *(const short8*)(w2t + (m16 + 16) * 32 + q4 * 8);
  float m0 = -INFINITY, m1 = -INFINITY;
  const int ntiles = (n + 15) >> 4;
  for (int rt = 0; rt < ntiles; ++rt) {
    const int row = rbase + rt * 16 + m16;
    short8 af = *(const short8*)(hbuf + row * 32 +
                                 ((q4 ^ ((row >> 1) & 3)) << 3));
    floatx4 z = {0.f, 0.f, 0.f, 0.f};
    floatx4 a0 = __builtin_amdgcn_mfma_f32_16x16x32_bf16(af, bf0, z, 0, 0, 0);
    floatx4 a1 = __builtin_amdgcn_mfma_f32_16x16x32_bf16(af, bf1, z, 0, 0, 0);
    const int rowb = rt * 16 + q4 * 4;
#pragma unroll
    for (int r = 0; r < 4; ++r) {
      if (rowb + r < n) {              // mask tail-tile garbage rows
        m0 = fmaxf(m0, a0[r]);
        m1 = fmaxf(m1, a1[r]);
      }
    }
  }
  m0 = fmaxf(m0, __shfl_xor(m0, 16));
  m0 = fmaxf(m0, __shfl_xor(m0, 32));
  m1 = fmaxf(m1, __shfl_xor(m1, 16));
  m1 = fmaxf(m1, __shfl_xor(m1, 32));

  if (lane < 32) {
    float q = (lane & 16) ? m1 : m0;
    out[p * 32 + lane] = fmaxf(q + pc, 0.f);   // relu(max+pc): s2>0 monotone
  }
}

extern "C" void kernel_launch(void* const* d_in, const int* in_sizes, int n_in,
                              void* d_out, int out_size, void* d_ws, size_t ws_size,
                              hipStream_t stream) {
  const float* points = (const float*)d_in[0];
  const float* fc     = (const float*)d_in[1];
  const int*   unq    = (const int*)d_in[2];
  const float* W1 = (const float*)d_in[3];
  const float* g1 = (const float*)d_in[4];
  const float* b1 = (const float*)d_in[5];
  const float* m1 = (const float*)d_in[6];
  const float* v1 = (const float*)d_in[7];
  const float* W2 = (const float*)d_in[8];
  const float* g2 = (const float*)d_in[9];
  const float* b2 = (const float*)d_in[10];
  const float* m2 = (const float*)d_in[11];
  const float* v2 = (const float*)d_in[12];

  const int N    = in_sizes[0] / 5;  // 1,000,000
  const int NPIL = out_size / 32;    // 30,000

  float* ws = (float*)d_ws;
  int* tails = (int*)ws;
  float* prep = ws + 4096;
  float* row8 = prep + PREP_F;
  int2* cbuf = (int2*)(row8 + (size_t)N * 8);
  int2* fgbuf = cbuf + (size_t)59 * CCAP;

  k_prep_row8<<<(N + 255) / 256, 256, 0, stream>>>(points, fc, tails, row8,
                                                   W1, g1, b1, m1, v1,
                                                   W2, g2, b2, m2, v2, prep, N);

  k_bin1<<<(N + 2047) / 2048, 256, 0, stream>>>(unq, tails, cbuf, N);

  k_bin2<<<59 * 10, 256, 0, stream>>>(tails, tails, cbuf, fgbuf);

  const int nfb = (NPIL + 7) / 8;    // 3750
  k_pillar<<<nfb, 512, 0, stream>>>(prep, tails, fgbuf, row8,
                                    (float*)d_out, NPIL);
}